// Round 1
// 414.201 us; speedup vs baseline: 1.0022x; 1.0022x over previous
//
#include <hip/hip_runtime.h>
#include <stdint.h>

typedef __attribute__((ext_vector_type(8))) short short8;   // 8 x bf16 MFMA operand
typedef __attribute__((ext_vector_type(4))) float floatx4;  // MFMA accumulator

#define DEV __device__ __forceinline__

DEV unsigned short f2bf(float x) {  // fp32 -> bf16 RNE (epilogue-only; hot paths use pkbf)
  unsigned u = __float_as_uint(x);
  u += 0x7fffu + ((u >> 16) & 1u);
  return (unsigned short)(u >> 16);
}

// pack two fp32 -> two bf16 (round-half-up) in 3 VALU: 2 adds + v_perm
// dst low16 = bf16(lo), high16 = bf16(hi)
DEV unsigned pkbf(float hi, float lo) {
  return __builtin_amdgcn_perm(__float_as_uint(hi) + 0x8000u,
                               __float_as_uint(lo) + 0x8000u, 0x07060302u);
}

DEV void load_lds16(const unsigned short* g, unsigned short* l) {
  __builtin_amdgcn_global_load_lds(
      (const __attribute__((address_space(1))) void*)g,
      (__attribute__((address_space(3))) void*)l, 16, 0, 0);
}

DEV void lds_fence() { asm volatile("" ::: "memory"); }  // wave-private LDS RAW/WAR ordering

// ---------------- one-shot fp32 -> bf16 of all 7 tensors ----------------
// blocks 0..4095: weights (4 x 1M floats, contiguous out). 4096..28671: activations.
__global__ void cvt_all(const float* __restrict__ Wq, const float* __restrict__ Wk,
                        const float* __restrict__ Wv, const float* __restrict__ Wo,
                        const float* __restrict__ Xq, const float* __restrict__ Xk,
                        const float* __restrict__ Xv,
                        unsigned short* __restrict__ Wb, unsigned short* __restrict__ XqB,
                        unsigned short* __restrict__ XkB, unsigned short* __restrict__ XvB) {
  int bid = blockIdx.x;
  const float* src;
  unsigned short* dst;
  int off;
  if (bid < 4096) {
    int sel = bid >> 10;
    src = sel == 0 ? Wq : sel == 1 ? Wk : sel == 2 ? Wv : Wo;
    dst = Wb + (size_t)sel * 1048576;
    off = bid & 1023;
  } else {
    bid -= 4096;
    int sel = bid >> 13;
    src = sel == 0 ? Xq : sel == 1 ? Xk : Xv;
    dst = sel == 0 ? XqB : sel == 1 ? XkB : XvB;
    off = bid & 8191;
  }
  int i = (off * 256 + threadIdx.x) * 4;
  float4 v = *(const float4*)(src + i);
  uint2 o;
  o.x = pkbf(v.y, v.x);
  o.y = pkbf(v.w, v.z);
  *(uint2*)(dst + i) = o;
}

// ---------------- fused QKV projection: double-buffered 2-phase pipeline, grid (8,64,3) ------
// z=0: Qp[b,h,s,64] = (q@Wq^T+bq) * SCQ  (softmax scale folded in, base-2 units)
// z=1: Kp[b,h,s,64] = k@Wk^T+bk
// z=2: VTp[b,h,64,s] = (v@Wv^T+bv)^T  (A/B operand roles swapped)
#define SCQ (0.125f * 1.44269504089f)
__global__ __launch_bounds__(256, 2) void qkv_gemm(
    const unsigned short* __restrict__ XqB, const unsigned short* __restrict__ XkB,
    const unsigned short* __restrict__ XvB,
    const unsigned short* __restrict__ Wb,
    const float* __restrict__ bq, const float* __restrict__ bk, const float* __restrict__ bv,
    unsigned short* __restrict__ Qp, unsigned short* __restrict__ Kp,
    unsigned short* __restrict__ VTp) {
  __shared__ alignas(16) unsigned short Xs[2][128 * 32];
  __shared__ alignas(16) unsigned short Ws[2][128 * 32];
  const int z = blockIdx.z;
  const unsigned short* X = z == 0 ? XqB : z == 1 ? XkB : XvB;
  const unsigned short* W = Wb + (size_t)z * 1048576;
  const float* bias = z == 0 ? bq : z == 1 ? bk : bv;

  const int tid = threadIdx.x;
  const int lane = tid & 63, wave = tid >> 6;
  const int lcol = lane & 15, quad = lane >> 4;
  const int wo = blockIdx.x * 128;  // d origin (weight rows)
  const int xo = blockIdx.y * 128;  // s origin (input rows)
  const int wm = (wave & 1) * 64;
  const int wn = (wave >> 1) * 64;

  floatx4 acc[4][4];
  for (int mi = 0; mi < 4; ++mi)
    for (int ni = 0; ni < 4; ++ni)
      for (int r = 0; r < 4; ++r) acc[mi][ni][r] = 0.f;

  // prologue: stage k-tile 0 into buffer 0
  {
    int c = tid;
    load_lds16(W + (size_t)(wo + (c >> 2)) * 1024 + (c & 3) * 8, Ws[0] + c * 8);
    load_lds16(X + (size_t)(xo + (c >> 2)) * 1024 + (c & 3) * 8, Xs[0] + c * 8);
    c = tid + 256;
    load_lds16(W + (size_t)(wo + (c >> 2)) * 1024 + (c & 3) * 8, Ws[0] + c * 8);
    load_lds16(X + (size_t)(xo + (c >> 2)) * 1024 + (c & 3) * 8, Xs[0] + c * 8);
  }
  __syncthreads();

  for (int kt = 0; kt < 32; ++kt) {
    const int cur = kt & 1;
    if (kt != 31) {  // stage next tile into other buffer; waited at end-of-iter barrier
      const int k0 = (kt + 1) * 32;
      int c = tid;
      load_lds16(W + (size_t)(wo + (c >> 2)) * 1024 + k0 + (c & 3) * 8, Ws[cur ^ 1] + c * 8);
      load_lds16(X + (size_t)(xo + (c >> 2)) * 1024 + k0 + (c & 3) * 8, Xs[cur ^ 1] + c * 8);
      c = tid + 256;
      load_lds16(W + (size_t)(wo + (c >> 2)) * 1024 + k0 + (c & 3) * 8, Ws[cur ^ 1] + c * 8);
      load_lds16(X + (size_t)(xo + (c >> 2)) * 1024 + k0 + (c & 3) * 8, Xs[cur ^ 1] + c * 8);
    }
    const unsigned short* Ab = (z < 2) ? Xs[cur] : Ws[cur];  // MFMA A operand rows (m)
    const unsigned short* Bb = (z < 2) ? Ws[cur] : Xs[cur];  // MFMA B operand rows (n)
    short8 af[4], bfr[4];
#pragma unroll
    for (int mi = 0; mi < 4; ++mi)
      af[mi] = *(const short8*)(Ab + (wm + mi * 16 + lcol) * 32 + quad * 8);
#pragma unroll
    for (int ni = 0; ni < 4; ++ni)
      bfr[ni] = *(const short8*)(Bb + (wn + ni * 16 + lcol) * 32 + quad * 8);
#pragma unroll
    for (int mi = 0; mi < 4; ++mi)
#pragma unroll
      for (int ni = 0; ni < 4; ++ni)
        acc[mi][ni] = __builtin_amdgcn_mfma_f32_16x16x32_bf16(af[mi], bfr[ni], acc[mi][ni], 0, 0, 0);
    __syncthreads();  // waits vmcnt(0): next tile landed; all waves done reading cur
  }

  if (z < 2) {  // C[m=s][n=d] -> head-split [B,H,S,64]
    unsigned short* Out = z == 0 ? Qp : Kp;
    const float scl = z == 0 ? SCQ : 1.f;
#pragma unroll
    for (int ni = 0; ni < 4; ++ni) {
      int col = wo + wn + ni * 16 + lcol;
      float bvx = bias[col];
      int h = col >> 6, d = col & 63;
#pragma unroll
      for (int mi = 0; mi < 4; ++mi) {
        int rbase = xo + wm + mi * 16 + quad * 4;
#pragma unroll
        for (int r = 0; r < 4; ++r) {
          int grow = rbase + r;            // = b*2048 + s
          int bb = grow >> 11, s = grow & 2047;
          Out[((size_t)(bb * 16 + h) * 2048 + s) * 64 + d] = f2bf((acc[mi][ni][r] + bvx) * scl);
        }
      }
    }
  } else {  // C[m=d][n=s] -> V^T [B,H,64,S]
#pragma unroll
    for (int mi = 0; mi < 4; ++mi) {
      int dbase = wo + wm + mi * 16 + quad * 4;
#pragma unroll
      for (int r = 0; r < 4; ++r) {
        int dg = dbase + r;
        float bvx = bias[dg];
        int h = dg >> 6, dk = dg & 63;
#pragma unroll
        for (int ni = 0; ni < 4; ++ni) {
          int sg = xo + wn + ni * 16 + lcol;  // = b*2048 + s
          int bb = sg >> 11, ss = sg & 2047;
          VTp[((size_t)(bb * 16 + h) * 64 + dk) * 2048 + ss] = f2bf(acc[mi][ni][r] + bvx);
        }
      }
    }
  }
}

// ---------------- final O-projection: fp32 out, double-buffered 2-phase ----------------
__global__ __launch_bounds__(256, 2) void gemm_o(
    const unsigned short* __restrict__ A, const unsigned short* __restrict__ Bw,
    const float* __restrict__ bias, float* __restrict__ Out) {
  __shared__ alignas(16) unsigned short As[2][128 * 32];
  __shared__ alignas(16) unsigned short Bs[2][128 * 32];
  const int tid = threadIdx.x;
  const int lane = tid & 63, wave = tid >> 6;
  const int lcol = lane & 15, quad = lane >> 4;
  const int n0 = blockIdx.x * 128;
  const int m0 = blockIdx.y * 128;
  const int wm = (wave & 1) * 64;
  const int wn = (wave >> 1) * 64;

  floatx4 acc[4][4];
  for (int mi = 0; mi < 4; ++mi)
    for (int ni = 0; ni < 4; ++ni)
      for (int r = 0; r < 4; ++r) acc[mi][ni][r] = 0.f;

  {
    int c = tid;
    load_lds16(Bw + (size_t)(n0 + (c >> 2)) * 1024 + (c & 3) * 8, Bs[0] + c * 8);
    load_lds16(A  + (size_t)(m0 + (c >> 2)) * 1024 + (c & 3) * 8, As[0] + c * 8);
    c = tid + 256;
    load_lds16(Bw + (size_t)(n0 + (c >> 2)) * 1024 + (c & 3) * 8, Bs[0] + c * 8);
    load_lds16(A  + (size_t)(m0 + (c >> 2)) * 1024 + (c & 3) * 8, As[0] + c * 8);
  }
  __syncthreads();

  for (int kt = 0; kt < 32; ++kt) {
    const int cur = kt & 1;
    if (kt != 31) {
      const int k0 = (kt + 1) * 32;
      int c = tid;
      load_lds16(Bw + (size_t)(n0 + (c >> 2)) * 1024 + k0 + (c & 3) * 8, Bs[cur ^ 1] + c * 8);
      load_lds16(A  + (size_t)(m0 + (c >> 2)) * 1024 + k0 + (c & 3) * 8, As[cur ^ 1] + c * 8);
      c = tid + 256;
      load_lds16(Bw + (size_t)(n0 + (c >> 2)) * 1024 + k0 + (c & 3) * 8, Bs[cur ^ 1] + c * 8);
      load_lds16(A  + (size_t)(m0 + (c >> 2)) * 1024 + k0 + (c & 3) * 8, As[cur ^ 1] + c * 8);
    }
    short8 af[4], bfr[4];
#pragma unroll
    for (int mi = 0; mi < 4; ++mi)
      af[mi] = *(const short8*)(As[cur] + (wm + mi * 16 + lcol) * 32 + quad * 8);
#pragma unroll
    for (int ni = 0; ni < 4; ++ni)
      bfr[ni] = *(const short8*)(Bs[cur] + (wn + ni * 16 + lcol) * 32 + quad * 8);
#pragma unroll
    for (int mi = 0; mi < 4; ++mi)
#pragma unroll
      for (int ni = 0; ni < 4; ++ni)
        acc[mi][ni] = __builtin_amdgcn_mfma_f32_16x16x32_bf16(af[mi], bfr[ni], acc[mi][ni], 0, 0, 0);
    __syncthreads();
  }
#pragma unroll
  for (int ni = 0; ni < 4; ++ni) {
    int col = n0 + wn + ni * 16 + lcol;
    float bv = bias[col];
#pragma unroll
    for (int mi = 0; mi < 4; ++mi) {
      int rbase = m0 + wm + mi * 16 + quad * 4;
#pragma unroll
      for (int r = 0; r < 4; ++r)
        Out[(size_t)(rbase + r) * 1024 + col] = acc[mi][ni][r] + bv;
    }
  }
}

// ---------------- flash attention: one block = (b, h, 128 q rows) ----------------
// This round: double-buffered K/V tiles + dedicated P buffer -> 1 barrier/iter (was 3),
// staging latency hidden under previous iteration's compute; defer-max (THR=8 base-2);
// vectorized (pk-f32-friendly) softmax sub/sum/rescale; max3-friendly reduction tree.
__global__ __launch_bounds__(256, 2) void attn_kernel(
    const unsigned short* __restrict__ Qp, const unsigned short* __restrict__ Kp,
    const unsigned short* __restrict__ VTp, unsigned short* __restrict__ Ctx) {
  __shared__ alignas(16) unsigned short Ks[2][128 * 64];  // K tiles (double-buffered)
  __shared__ alignas(16) unsigned short Vt[2][64 * 128];  // V^T tiles (double-buffered)
  __shared__ alignas(16) unsigned short Ps[128 * 64];     // Q stage -> P -> O stage

  const int tid = threadIdx.x;
  const int lane = tid & 63, wave = tid >> 6;
  const int lcol = lane & 15, quad = lane >> 4;
  const int wq = wave * 32;
  const int qt = blockIdx.x, h = blockIdx.y, b = blockIdx.z;
  const size_t bh = (size_t)(b * 16 + h) * 2048 * 64;
  const unsigned short* Qb = Qp + bh + (size_t)qt * 128 * 64;
  const unsigned short* Kb = Kp + bh;
  const unsigned short* VTb = VTp + (size_t)(b * 16 + h) * 64 * 2048;

  // prologue: Q tile into Ps (swizzled) + stage K/V tile 0 into buffer 0
#pragma unroll
  for (int i = 0; i < 4; ++i) {
    int p = tid + i * 256;
    int row = p >> 3, pj = p & 7;
    load_lds16(Qb + row * 64 + ((pj ^ (row & 7)) * 8), Ps + p * 8);
  }
#pragma unroll
  for (int i = 0; i < 4; ++i) {
    int p = tid + i * 256;
    int kr = p >> 3, kj = p & 7;
    load_lds16(Kb + kr * 64 + ((kj ^ (kr & 7)) * 8), Ks[0] + p * 8);
    int vr = p >> 4, vj = p & 15;
    load_lds16(VTb + (size_t)vr * 2048 + ((vj ^ (vr & 7)) * 8), Vt[0] + p * 8);
  }
  __syncthreads();  // Q + tile0 resident

  short8 qf[2][2];
#pragma unroll
  for (int ni = 0; ni < 2; ++ni)
#pragma unroll
    for (int ks = 0; ks < 2; ++ks) {
      int row = wq + ni * 16 + lcol;
      qf[ni][ks] = *(const short8*)(Ps + row * 64 + (((ks * 4 + quad) ^ (row & 7)) * 8));
    }

  float M[2] = {-1e30f, -1e30f};
  float L[2] = {0.f, 0.f};
  floatx4 Oacc[2][4];
  for (int mi = 0; mi < 2; ++mi)
    for (int nd = 0; nd < 4; ++nd)
      for (int r = 0; r < 4; ++r) Oacc[mi][nd][r] = 0.f;

  for (int jt = 0; jt < 16; ++jt) {
    const int cur = jt & 1;
    if (jt != 15) {  // prefetch next K/V tile into other buffer (WAR-safe: barrier at end of jt-1)
#pragma unroll
      for (int i = 0; i < 4; ++i) {
        int p = tid + i * 256;
        int kr = p >> 3, kj = p & 7;
        load_lds16(Kb + (size_t)(jt + 1) * 8192 + kr * 64 + ((kj ^ (kr & 7)) * 8),
                   Ks[cur ^ 1] + p * 8);
        int vr = p >> 4, vj = p & 15;
        load_lds16(VTb + (size_t)vr * 2048 + (jt + 1) * 128 + ((vj ^ (vr & 7)) * 8),
                   Vt[cur ^ 1] + p * 8);
      }
    }

    // S^T = K @ Q^T  (Q pre-scaled: sacc already in base-2 logit units)
    const unsigned short* Kc = Ks[cur];
    floatx4 sacc[8][2];
    for (int mi = 0; mi < 8; ++mi)
      for (int ni = 0; ni < 2; ++ni)
        for (int r = 0; r < 4; ++r) sacc[mi][ni][r] = 0.f;
#pragma unroll
    for (int mi = 0; mi < 8; ++mi) {
      int row = mi * 16 + lcol;
      int sw = (row & 7);
      short8 kf0 = *(const short8*)(Kc + row * 64 + ((quad ^ sw) * 8));
      short8 kf1 = *(const short8*)(Kc + row * 64 + (((4 + quad) ^ sw) * 8));
#pragma unroll
      for (int ni = 0; ni < 2; ++ni) {
        sacc[mi][ni] = __builtin_amdgcn_mfma_f32_16x16x32_bf16(kf0, qf[ni][0], sacc[mi][ni], 0, 0, 0);
        sacc[mi][ni] = __builtin_amdgcn_mfma_f32_16x16x32_bf16(kf1, qf[ni][1], sacc[mi][ni], 0, 0, 0);
      }
    }

    // ---- online softmax over kcol (defer-max: skip rescale when max grew <= 8) ----
    float mx[2];
#pragma unroll
    for (int ni = 0; ni < 2; ++ni) {
      float pm[8];
#pragma unroll
      for (int mi = 0; mi < 8; ++mi)
        pm[mi] = fmaxf(fmaxf(sacc[mi][ni][0], sacc[mi][ni][1]),
                       fmaxf(sacc[mi][ni][2], sacc[mi][ni][3]));
      float t0 = fmaxf(fmaxf(pm[0], pm[1]), fmaxf(pm[2], pm[3]));
      float t1 = fmaxf(fmaxf(pm[4], pm[5]), fmaxf(pm[6], pm[7]));
      float m = fmaxf(t0, t1);
      m = fmaxf(m, __shfl_xor(m, 16));
      m = fmaxf(m, __shfl_xor(m, 32));
      mx[ni] = m;
    }
    const int skip = __all((mx[0] <= M[0] + 8.f) & (mx[1] <= M[1] + 8.f));
    float alpha[2] = {1.f, 1.f};
    if (!skip) {
#pragma unroll
      for (int ni = 0; ni < 2; ++ni) {
        float mnew = fmaxf(M[ni], mx[ni]);
        alpha[ni] = exp2f(M[ni] - mnew);
        M[ni] = mnew;
      }
      // rescale O (alpha is quad-uniform; fetch C-layout row's alpha by shuffle)
#pragma unroll
      for (int mi = 0; mi < 2; ++mi)
#pragma unroll
        for (int r = 0; r < 4; ++r) {
          float a = __shfl(alpha[mi], quad * 4 + r);
          floatx4 av = {a, a, a, a};
#pragma unroll
          for (int nd = 0; nd < 4; ++nd) Oacc[mi][nd] *= av;
        }
    }
#pragma unroll
    for (int ni = 0; ni < 2; ++ni) {
      floatx4 mv = {M[ni], M[ni], M[ni], M[ni]};
      floatx4 rv = {0.f, 0.f, 0.f, 0.f};
#pragma unroll
      for (int mi = 0; mi < 8; ++mi) {
        floatx4 t = sacc[mi][ni] - mv;  // pk-f32 friendly
        floatx4 p;
        p[0] = exp2f(t[0]); p[1] = exp2f(t[1]); p[2] = exp2f(t[2]); p[3] = exp2f(t[3]);
        sacc[mi][ni] = p;
        rv += p;
      }
      float rs = (rv[0] + rv[1]) + (rv[2] + rv[3]);
      rs += __shfl_xor(rs, 16);
      rs += __shfl_xor(rs, 32);
      L[ni] = skip ? (L[ni] + rs) : (L[ni] * alpha[ni] + rs);
    }

    // P (2 halves of 64 kcols) -> Ps; perm-packed writes; fence-ordered (wave-private rows)
    const unsigned short* Vc = Vt[cur];
#pragma unroll
    for (int half = 0; half < 2; ++half) {
#pragma unroll
      for (int ni = 0; ni < 2; ++ni) {
        int q = wq + ni * 16 + lcol;
        int sw = q & 7;
#pragma unroll
        for (int m2 = 0; m2 < 4; ++m2) {
          int mi = half * 4 + m2;
          uint2 pw;
          pw.x = pkbf(sacc[mi][ni][1], sacc[mi][ni][0]);
          pw.y = pkbf(sacc[mi][ni][3], sacc[mi][ni][2]);
          int j = 2 * m2 + (quad >> 1);
          *(uint2*)(Ps + q * 64 + ((j ^ sw) * 8) + (quad & 1) * 4) = pw;
        }
      }
      lds_fence();
#pragma unroll
      for (int kk = 0; kk < 2; ++kk) {
        short8 pf[2];
#pragma unroll
        for (int mi = 0; mi < 2; ++mi) {
          int q = wq + mi * 16 + lcol;
          pf[mi] = *(const short8*)(Ps + q * 64 + (((4 * kk + quad) ^ (q & 7)) * 8));
        }
#pragma unroll
        for (int nd = 0; nd < 4; ++nd) {
          int d = nd * 16 + lcol;
          short8 vf = *(const short8*)(Vc + d * 128 + ((((half * 2 + kk) * 4 + quad) ^ (d & 7)) * 8));
#pragma unroll
          for (int mi = 0; mi < 2; ++mi)
            Oacc[mi][nd] = __builtin_amdgcn_mfma_f32_16x16x32_bf16(pf[mi], vf, Oacc[mi][nd], 0, 0, 0);
        }
      }
      lds_fence();
    }
    __syncthreads();  // next tile landed (vmcnt 0); all waves done with cur bufs
  }

  // epilogue: O/L -> bf16 into Ps (swizzled), then coalesced store
  float linv[2] = {1.f / L[0], 1.f / L[1]};
#pragma unroll
  for (int mi = 0; mi < 2; ++mi)
#pragma unroll
    for (int r = 0; r < 4; ++r) {
      float li = __shfl(linv[mi], quad * 4 + r);
      int q = wq + mi * 16 + quad * 4 + r;
      int sw = q & 7;
#pragma unroll
      for (int nd = 0; nd < 4; ++nd) {
        int j = 2 * nd + (lcol >> 3);
        Ps[q * 64 + ((j ^ sw) * 8) + (lcol & 7)] = f2bf(Oacc[mi][nd][r] * li);
      }
    }
  __syncthreads();
#pragma unroll
  for (int i = 0; i < 4; ++i) {
    int c = tid + i * 256;
    int row = c >> 3, pj = c & 7;
    uint4 v = *(const uint4*)(Ps + row * 64 + ((pj ^ (row & 7)) * 8));
    *(uint4*)(Ctx + ((size_t)(b * 2048 + qt * 128 + row)) * 1024 + h * 64 + pj * 8) = v;
  }
}

// ---------------- launch ----------------
extern "C" void kernel_launch(void* const* d_in, const int* in_sizes, int n_in,
                              void* d_out, int out_size, void* d_ws, size_t ws_size,
                              hipStream_t stream) {
  const float* query = (const float*)d_in[0];
  const float* key_  = (const float*)d_in[1];
  const float* value = (const float*)d_in[2];
  const float* Wq = (const float*)d_in[3];
  const float* bq = (const float*)d_in[4];
  const float* Wk = (const float*)d_in[5];
  const float* bk = (const float*)d_in[6];
  const float* Wv = (const float*)d_in[7];
  const float* bv = (const float*)d_in[8];
  const float* Wo = (const float*)d_in[9];
  const float* bo = (const float*)d_in[10];

  char* w = (char*)d_ws;
  unsigned short* Wb  = (unsigned short*)w; w += (size_t)4 * 1024 * 1024 * 2;  // Wq,Wk,Wv,Wo bf16
  unsigned short* Qp  = (unsigned short*)w; w += (size_t)8192 * 1024 * 2;      // [B,H,S,64]
  unsigned short* Kp  = (unsigned short*)w; w += (size_t)8192 * 1024 * 2;      // [B,H,S,64]
  unsigned short* VTp = (unsigned short*)w; w += (size_t)8192 * 1024 * 2;      // [B,H,64,S]
  unsigned short* Ctx = (unsigned short*)w; w += (size_t)8192 * 1024 * 2;      // [B,S,1024]

  // bf16 activations: query/key park in d_out (32 MB, dead until gemm_o);
  // value parks in the Ctx slot (dead once qkv_gemm completes, before attn writes Ctx).
  unsigned short* XqB = (unsigned short*)d_out;
  unsigned short* XkB = (unsigned short*)d_out + (size_t)8192 * 1024;
  unsigned short* XvB = Ctx;

  cvt_all<<<28672, 256, 0, stream>>>(Wq, Wk, Wv, Wo, query, key_, value,
                                     Wb, XqB, XkB, XvB);

  qkv_gemm<<<dim3(8, 64, 3), 256, 0, stream>>>(XqB, XkB, XvB, Wb,
                                               bq, bk, bv, Qp, Kp, VTp);

  attn_kernel<<<dim3(16, 16, 4), 256, 0, stream>>>(Qp, Kp, VTp, Ctx);

  gemm_o<<<dim3(8, 64), 256, 0, stream>>>(Ctx, Wb + (size_t)3 * 1048576, bo, (float*)d_out);
}

// Round 2
// 400.814 us; speedup vs baseline: 1.0357x; 1.0334x over previous
//
#include <hip/hip_runtime.h>
#include <stdint.h>

typedef __attribute__((ext_vector_type(8))) short short8;   // 8 x bf16 MFMA operand
typedef __attribute__((ext_vector_type(4))) float floatx4;  // MFMA accumulator

#define DEV __device__ __forceinline__

DEV unsigned short f2bf(float x) {  // fp32 -> bf16 RNE (epilogue-only; hot paths use pkbf)
  unsigned u = __float_as_uint(x);
  u += 0x7fffu + ((u >> 16) & 1u);
  return (unsigned short)(u >> 16);
}

// pack two fp32 -> two bf16 (round-half-up) in 3 VALU: 2 adds + v_perm
DEV unsigned pkbf(float hi, float lo) {
  return __builtin_amdgcn_perm(__float_as_uint(hi) + 0x8000u,
                               __float_as_uint(lo) + 0x8000u, 0x07060302u);
}

DEV void load_lds16(const unsigned short* g, unsigned short* l) {
  __builtin_amdgcn_global_load_lds(
      (const __attribute__((address_space(1))) void*)g,
      (__attribute__((address_space(3))) void*)l, 16, 0, 0);
}

DEV void lds_fence() { asm volatile("" ::: "memory"); }  // wave-private LDS RAW/WAR ordering

// counted vmcnt + raw barrier (T4): never drain to 0 mid-loop
#define ASM_VMCNT(n) asm volatile("s_waitcnt vmcnt(" #n ")" ::: "memory")
DEV void sched_fence() { __builtin_amdgcn_sched_barrier(0); }

// ---------------- one-shot fp32 -> bf16 of all 7 tensors ----------------
__global__ void cvt_all(const float* __restrict__ Wq, const float* __restrict__ Wk,
                        const float* __restrict__ Wv, const float* __restrict__ Wo,
                        const float* __restrict__ Xq, const float* __restrict__ Xk,
                        const float* __restrict__ Xv,
                        unsigned short* __restrict__ Wb, unsigned short* __restrict__ XqB,
                        unsigned short* __restrict__ XkB, unsigned short* __restrict__ XvB) {
  int bid = blockIdx.x;
  const float* src;
  unsigned short* dst;
  int off;
  if (bid < 4096) {
    int sel = bid >> 10;
    src = sel == 0 ? Wq : sel == 1 ? Wk : sel == 2 ? Wv : Wo;
    dst = Wb + (size_t)sel * 1048576;
    off = bid & 1023;
  } else {
    bid -= 4096;
    int sel = bid >> 13;
    src = sel == 0 ? Xq : sel == 1 ? Xk : Xv;
    dst = sel == 0 ? XqB : sel == 1 ? XkB : XvB;
    off = bid & 8191;
  }
  int i = (off * 256 + threadIdx.x) * 4;
  float4 v = *(const float4*)(src + i);
  uint2 o;
  o.x = pkbf(v.y, v.x);
  o.y = pkbf(v.w, v.z);
  *(uint2*)(dst + i) = o;
}

// ---------------- fused QKV projection: depth-2 counted-vmcnt pipeline, grid (8,64,3) --------
// Operand roles: z<2: A=W (m=d), B=X (n=s)  -> lane holds 4 consecutive d -> uint2 stores
//                z=2: A=X (m=s), B=W (n=d)  -> lane holds 4 consecutive s -> uint2 stores (V^T)
#define SCQ (0.125f * 1.44269504089f)
__global__ __launch_bounds__(256, 3) void qkv_gemm(
    const unsigned short* __restrict__ XqB, const unsigned short* __restrict__ XkB,
    const unsigned short* __restrict__ XvB,
    const unsigned short* __restrict__ Wb,
    const float* __restrict__ bq, const float* __restrict__ bk, const float* __restrict__ bv,
    unsigned short* __restrict__ Qp, unsigned short* __restrict__ Kp,
    unsigned short* __restrict__ VTp) {
  __shared__ alignas(16) unsigned short Xs[3][128 * 32];
  __shared__ alignas(16) unsigned short Ws[3][128 * 32];
  const int z = blockIdx.z;
  const unsigned short* X = z == 0 ? XqB : z == 1 ? XkB : XvB;
  const unsigned short* W = Wb + (size_t)z * 1048576;
  const float* bias = z == 0 ? bq : z == 1 ? bk : bv;

  const int tid = threadIdx.x;
  const int lane = tid & 63, wave = tid >> 6;
  const int lcol = lane & 15, quad = lane >> 4;
  const int wo = blockIdx.x * 128;  // d origin (weight rows)
  const int xo = blockIdx.y * 128;  // s origin (input rows)
  const int wm = (wave & 1) * 64;
  const int wn = (wave >> 1) * 64;

  floatx4 acc[4][4];
  for (int mi = 0; mi < 4; ++mi)
    for (int ni = 0; ni < 4; ++ni)
      for (int r = 0; r < 4; ++r) acc[mi][ni][r] = 0.f;

  auto stage = [&](int kt, int buf) {  // 4 vmem ops / thread / tile
    const int k0 = kt * 32;
    int c = tid;
    load_lds16(W + (size_t)(wo + (c >> 2)) * 1024 + k0 + (c & 3) * 8, Ws[buf] + c * 8);
    load_lds16(X + (size_t)(xo + (c >> 2)) * 1024 + k0 + (c & 3) * 8, Xs[buf] + c * 8);
    c = tid + 256;
    load_lds16(W + (size_t)(wo + (c >> 2)) * 1024 + k0 + (c & 3) * 8, Ws[buf] + c * 8);
    load_lds16(X + (size_t)(xo + (c >> 2)) * 1024 + k0 + (c & 3) * 8, Xs[buf] + c * 8);
  };

  stage(0, 0);
  stage(1, 1);
  int cur = 0;
  for (int kt = 0; kt < 32; ++kt) {
    sched_fence();
    ASM_VMCNT(4);                    // tile kt landed; tile kt+1 still in flight
    __builtin_amdgcn_s_barrier();    // cross-wave visibility of tile kt
    sched_fence();
    int nb = cur + 2; if (nb >= 3) nb -= 3;
    stage((kt + 2) & 31, nb);        // wrap-issue keeps vmcnt count uniform at tail
    const unsigned short* Ab = (z < 2) ? Ws[cur] : Xs[cur];  // A rows (m)
    const unsigned short* Bb = (z < 2) ? Xs[cur] : Ws[cur];  // B rows (n)
    short8 af[4], bfr[4];
#pragma unroll
    for (int mi = 0; mi < 4; ++mi)
      af[mi] = *(const short8*)(Ab + (wm + mi * 16 + lcol) * 32 + quad * 8);
#pragma unroll
    for (int ni = 0; ni < 4; ++ni)
      bfr[ni] = *(const short8*)(Bb + (wn + ni * 16 + lcol) * 32 + quad * 8);
#pragma unroll
    for (int mi = 0; mi < 4; ++mi)
#pragma unroll
      for (int ni = 0; ni < 4; ++ni)
        acc[mi][ni] = __builtin_amdgcn_mfma_f32_16x16x32_bf16(af[mi], bfr[ni], acc[mi][ni], 0, 0, 0);
    cur = (cur == 2) ? 0 : cur + 1;
  }

  if (z < 2) {  // lane: d = base+quad*4+r (consecutive), s = ...+lcol -> packed uint2
    unsigned short* Out = z == 0 ? Qp : Kp;
    const float scl = z == 0 ? SCQ : 1.f;
#pragma unroll
    for (int mi = 0; mi < 4; ++mi) {
      int dbase = wo + wm + mi * 16 + quad * 4;
      float4 bv4 = *(const float4*)(bias + dbase);
      int h = dbase >> 6, dk = dbase & 63;
#pragma unroll
      for (int ni = 0; ni < 4; ++ni) {
        int sg = xo + wn + ni * 16 + lcol;  // = b*2048 + s
        int bb = sg >> 11, ss = sg & 2047;
        uint2 o;
        o.x = pkbf((acc[mi][ni][1] + bv4.y) * scl, (acc[mi][ni][0] + bv4.x) * scl);
        o.y = pkbf((acc[mi][ni][3] + bv4.w) * scl, (acc[mi][ni][2] + bv4.z) * scl);
        *(uint2*)(Out + ((size_t)(bb * 16 + h) * 2048 + ss) * 64 + dk) = o;
      }
    }
  } else {  // lane: s = base+quad*4+r (consecutive), d = ...+lcol -> packed uint2 into V^T
#pragma unroll
    for (int ni = 0; ni < 4; ++ni) {
      int dg = wo + wn + ni * 16 + lcol;
      float bvx = bias[dg];
      int h = dg >> 6, dk = dg & 63;
#pragma unroll
      for (int mi = 0; mi < 4; ++mi) {
        int sbase = xo + wm + mi * 16 + quad * 4;
        int bb = sbase >> 11, ss = sbase & 2047;
        uint2 o;
        o.x = pkbf(acc[mi][ni][1] + bvx, acc[mi][ni][0] + bvx);
        o.y = pkbf(acc[mi][ni][3] + bvx, acc[mi][ni][2] + bvx);
        *(uint2*)(VTp + ((size_t)(bb * 16 + h) * 64 + dk) * 2048 + ss) = o;
      }
    }
  }
}

// ---------------- final O-projection: fp32 out, depth-2 counted-vmcnt ----------------
// A=Wo (m=col, 4 consecutive per lane -> float4 stores), B=Ctx (n=s).
__global__ __launch_bounds__(256, 3) void gemm_o(
    const unsigned short* __restrict__ A, const unsigned short* __restrict__ Bw,
    const float* __restrict__ bias, float* __restrict__ Out) {
  __shared__ alignas(16) unsigned short Cs[3][128 * 32];
  __shared__ alignas(16) unsigned short Wos[3][128 * 32];
  const int tid = threadIdx.x;
  const int lane = tid & 63, wave = tid >> 6;
  const int lcol = lane & 15, quad = lane >> 4;
  const int co = blockIdx.x * 128;  // output-col block
  const int so = blockIdx.y * 128;  // s block
  const int wm = (wave & 1) * 64;
  const int wn = (wave >> 1) * 64;

  floatx4 acc[4][4];
  for (int mi = 0; mi < 4; ++mi)
    for (int ni = 0; ni < 4; ++ni)
      for (int r = 0; r < 4; ++r) acc[mi][ni][r] = 0.f;

  auto stage = [&](int kt, int buf) {
    const int k0 = kt * 32;
    int c = tid;
    load_lds16(Bw + (size_t)(co + (c >> 2)) * 1024 + k0 + (c & 3) * 8, Wos[buf] + c * 8);
    load_lds16(A  + (size_t)(so + (c >> 2)) * 1024 + k0 + (c & 3) * 8, Cs[buf] + c * 8);
    c = tid + 256;
    load_lds16(Bw + (size_t)(co + (c >> 2)) * 1024 + k0 + (c & 3) * 8, Wos[buf] + c * 8);
    load_lds16(A  + (size_t)(so + (c >> 2)) * 1024 + k0 + (c & 3) * 8, Cs[buf] + c * 8);
  };

  stage(0, 0);
  stage(1, 1);
  int cur = 0;
  for (int kt = 0; kt < 32; ++kt) {
    sched_fence();
    ASM_VMCNT(4);
    __builtin_amdgcn_s_barrier();
    sched_fence();
    int nb = cur + 2; if (nb >= 3) nb -= 3;
    stage((kt + 2) & 31, nb);
    short8 af[4], bfr[4];
#pragma unroll
    for (int mi = 0; mi < 4; ++mi)
      af[mi] = *(const short8*)(Wos[cur] + (wm + mi * 16 + lcol) * 32 + quad * 8);
#pragma unroll
    for (int ni = 0; ni < 4; ++ni)
      bfr[ni] = *(const short8*)(Cs[cur] + (wn + ni * 16 + lcol) * 32 + quad * 8);
#pragma unroll
    for (int mi = 0; mi < 4; ++mi)
#pragma unroll
      for (int ni = 0; ni < 4; ++ni)
        acc[mi][ni] = __builtin_amdgcn_mfma_f32_16x16x32_bf16(af[mi], bfr[ni], acc[mi][ni], 0, 0, 0);
    cur = (cur == 2) ? 0 : cur + 1;
  }
#pragma unroll
  for (int mi = 0; mi < 4; ++mi) {
    int cb = co + wm + mi * 16 + quad * 4;  // 4 consecutive output cols
    float4 bv4 = *(const float4*)(bias + cb);
#pragma unroll
    for (int ni = 0; ni < 4; ++ni) {
      int sg = so + wn + ni * 16 + lcol;
      float4 o;
      o.x = acc[mi][ni][0] + bv4.x;
      o.y = acc[mi][ni][1] + bv4.y;
      o.z = acc[mi][ni][2] + bv4.z;
      o.w = acc[mi][ni][3] + bv4.w;
      *(float4*)(Out + (size_t)sg * 1024 + cb) = o;
    }
  }
}

// ---------------- flash attention: one block = (b, h, 128 q rows) ----------------
// Round-2 structure: KVBLK=64, LDS=40KB exactly -> 4 blocks/CU (2x occupancy).
// K double-buffered (QK reads it at iter start); V single-buffered (issued at iter
// start, consumed ~800cy later in PV; guarded by counted vmcnt(2) + raw barrier so
// K(jt+1) stays in flight). Grid = 1024 blocks = full single-round residency.
__global__ __launch_bounds__(256, 4) void attn_kernel(
    const unsigned short* __restrict__ Qp, const unsigned short* __restrict__ Kp,
    const unsigned short* __restrict__ VTp, unsigned short* __restrict__ Ctx) {
  __shared__ alignas(16) unsigned short Ks[2][64 * 64];  // K tiles, dbuf (16KB)
  __shared__ alignas(16) unsigned short Vt[64 * 64];     // V^T tile (8KB)
  __shared__ alignas(16) unsigned short Ps[128 * 64];    // Q stage -> P -> O stage (16KB)

  const int tid = threadIdx.x;
  const int lane = tid & 63, wave = tid >> 6;
  const int lcol = lane & 15, quad = lane >> 4;
  const int wq = wave * 32;
  const int qt = blockIdx.x, h = blockIdx.y, b = blockIdx.z;
  const size_t bh = (size_t)(b * 16 + h) * 2048 * 64;
  const unsigned short* Qb = Qp + bh + (size_t)qt * 128 * 64;
  const unsigned short* Kb = Kp + bh;
  const unsigned short* VTb = VTp + (size_t)(b * 16 + h) * 64 * 2048;

  // prologue: Q tile into Ps (swizzled) + K tile 0 into Ks[0]
#pragma unroll
  for (int i = 0; i < 4; ++i) {
    int p = tid + i * 256;
    int row = p >> 3, pj = p & 7;
    load_lds16(Qb + row * 64 + ((pj ^ (row & 7)) * 8), Ps + p * 8);
  }
#pragma unroll
  for (int i = 0; i < 2; ++i) {
    int p = tid + i * 256;
    int kr = p >> 3, kj = p & 7;
    load_lds16(Kb + kr * 64 + ((kj ^ (kr & 7)) * 8), Ks[0] + p * 8);
  }
  __syncthreads();  // Q + K0 resident

  short8 qf[2][2];
#pragma unroll
  for (int ni = 0; ni < 2; ++ni)
#pragma unroll
    for (int ks = 0; ks < 2; ++ks) {
      int row = wq + ni * 16 + lcol;
      qf[ni][ks] = *(const short8*)(Ps + row * 64 + (((ks * 4 + quad) ^ (row & 7)) * 8));
    }

  float M[2] = {-1e30f, -1e30f};
  float L[2] = {0.f, 0.f};
  floatx4 Oacc[2][4];
  for (int mi = 0; mi < 2; ++mi)
    for (int nd = 0; nd < 4; ++nd)
      for (int r = 0; r < 4; ++r) Oacc[mi][nd][r] = 0.f;

  for (int jt = 0; jt < 32; ++jt) {
    const int cur = jt & 1;
    // issue V(jt) first (2 ops), then K(jt+1) (2 ops) -> vmcnt(2) waits exactly V
#pragma unroll
    for (int i = 0; i < 2; ++i) {
      int p = tid + i * 256;
      int vr = p >> 3, vj = p & 7;
      load_lds16(VTb + (size_t)vr * 2048 + jt * 64 + ((vj ^ (vr & 7)) * 8), Vt + p * 8);
    }
    const int jn = (jt + 1) & 31;  // wrap-issue at tail keeps vmcnt count uniform
#pragma unroll
    for (int i = 0; i < 2; ++i) {
      int p = tid + i * 256;
      int kr = p >> 3, kj = p & 7;
      load_lds16(Kb + (size_t)jn * 4096 + kr * 64 + ((kj ^ (kr & 7)) * 8), Ks[cur ^ 1] + p * 8);
    }

    // S^T = K @ Q^T  (Q pre-scaled: sacc already in base-2 logit units)
    const unsigned short* Kc = Ks[cur];
    floatx4 sacc[4][2];
    for (int mi = 0; mi < 4; ++mi)
      for (int ni = 0; ni < 2; ++ni)
        for (int r = 0; r < 4; ++r) sacc[mi][ni][r] = 0.f;
#pragma unroll
    for (int mi = 0; mi < 4; ++mi) {
      int row = mi * 16 + lcol;
      int sw = (row & 7);
      short8 kf0 = *(const short8*)(Kc + row * 64 + ((quad ^ sw) * 8));
      short8 kf1 = *(const short8*)(Kc + row * 64 + (((4 + quad) ^ sw) * 8));
#pragma unroll
      for (int ni = 0; ni < 2; ++ni) {
        sacc[mi][ni] = __builtin_amdgcn_mfma_f32_16x16x32_bf16(kf0, qf[ni][0], sacc[mi][ni], 0, 0, 0);
        sacc[mi][ni] = __builtin_amdgcn_mfma_f32_16x16x32_bf16(kf1, qf[ni][1], sacc[mi][ni], 0, 0, 0);
      }
    }

    // ---- online softmax over kcol (defer-max: skip rescale when max grew <= 8) ----
    float mx[2];
#pragma unroll
    for (int ni = 0; ni < 2; ++ni) {
      float pm[4];
#pragma unroll
      for (int mi = 0; mi < 4; ++mi)
        pm[mi] = fmaxf(fmaxf(sacc[mi][ni][0], sacc[mi][ni][1]),
                       fmaxf(sacc[mi][ni][2], sacc[mi][ni][3]));
      float m = fmaxf(fmaxf(pm[0], pm[1]), fmaxf(pm[2], pm[3]));
      m = fmaxf(m, __shfl_xor(m, 16));
      m = fmaxf(m, __shfl_xor(m, 32));
      mx[ni] = m;
    }
    const int skip = __all((mx[0] <= M[0] + 8.f) & (mx[1] <= M[1] + 8.f));
    float alpha[2] = {1.f, 1.f};
    if (!skip) {
#pragma unroll
      for (int ni = 0; ni < 2; ++ni) {
        float mnew = fmaxf(M[ni], mx[ni]);
        alpha[ni] = exp2f(M[ni] - mnew);
        M[ni] = mnew;
      }
#pragma unroll
      for (int mi = 0; mi < 2; ++mi)
#pragma unroll
        for (int r = 0; r < 4; ++r) {
          float a = __shfl(alpha[mi], quad * 4 + r);
          floatx4 av = {a, a, a, a};
#pragma unroll
          for (int nd = 0; nd < 4; ++nd) Oacc[mi][nd] *= av;
        }
    }
#pragma unroll
    for (int ni = 0; ni < 2; ++ni) {
      floatx4 mv = {M[ni], M[ni], M[ni], M[ni]};
      floatx4 rv = {0.f, 0.f, 0.f, 0.f};
#pragma unroll
      for (int mi = 0; mi < 4; ++mi) {
        floatx4 t = sacc[mi][ni] - mv;
        floatx4 p;
        p[0] = exp2f(t[0]); p[1] = exp2f(t[1]); p[2] = exp2f(t[2]); p[3] = exp2f(t[3]);
        sacc[mi][ni] = p;
        rv += p;
      }
      float rs = (rv[0] + rv[1]) + (rv[2] + rv[3]);
      rs += __shfl_xor(rs, 16);
      rs += __shfl_xor(rs, 32);
      L[ni] = skip ? (L[ni] + rs) : (L[ni] * alpha[ni] + rs);
    }

    // P -> Ps (wave-private rows); perm-packed writes; fence-ordered
#pragma unroll
    for (int ni = 0; ni < 2; ++ni) {
      int q = wq + ni * 16 + lcol;
      int sw = q & 7;
#pragma unroll
      for (int mi = 0; mi < 4; ++mi) {
        uint2 pw;
        pw.x = pkbf(sacc[mi][ni][1], sacc[mi][ni][0]);
        pw.y = pkbf(sacc[mi][ni][3], sacc[mi][ni][2]);
        int j = 2 * mi + (quad >> 1);
        *(uint2*)(Ps + q * 64 + ((j ^ sw) * 8) + (quad & 1) * 4) = pw;
      }
    }
    lds_fence();

    sched_fence();
    ASM_VMCNT(2);                  // V(jt) landed; K(jt+1) still in flight (T4)
    __builtin_amdgcn_s_barrier();  // B1: all waves' V-loads visible
    sched_fence();

    // PV from Vt & Ps
#pragma unroll
    for (int kk = 0; kk < 2; ++kk) {
      short8 pf[2];
#pragma unroll
      for (int mi = 0; mi < 2; ++mi) {
        int q = wq + mi * 16 + lcol;
        pf[mi] = *(const short8*)(Ps + q * 64 + (((kk * 4 + quad) ^ (q & 7)) * 8));
      }
#pragma unroll
      for (int nd = 0; nd < 4; ++nd) {
        int d = nd * 16 + lcol;
        short8 vf = *(const short8*)(Vt + d * 64 + (((kk * 4 + quad) ^ (d & 7)) * 8));
#pragma unroll
        for (int mi = 0; mi < 2; ++mi)
          Oacc[mi][nd] = __builtin_amdgcn_mfma_f32_16x16x32_bf16(pf[mi], vf, Oacc[mi][nd], 0, 0, 0);
      }
    }
    lds_fence();
    __syncthreads();  // B2: K(jt+1) landed (vmcnt 0) + all waves done with Vt/Ks[cur]
  }

  // epilogue: O/L -> bf16 into Ps (swizzled, wave-private rows), then coalesced store
  float linv[2] = {1.f / L[0], 1.f / L[1]};
#pragma unroll
  for (int mi = 0; mi < 2; ++mi)
#pragma unroll
    for (int r = 0; r < 4; ++r) {
      float li = __shfl(linv[mi], quad * 4 + r);
      int q = wq + mi * 16 + quad * 4 + r;
      int sw = q & 7;
#pragma unroll
      for (int nd = 0; nd < 4; ++nd) {
        int j = 2 * nd + (lcol >> 3);
        Ps[q * 64 + ((j ^ sw) * 8) + (lcol & 7)] = f2bf(Oacc[mi][nd][r] * li);
      }
    }
  __syncthreads();
#pragma unroll
  for (int i = 0; i < 4; ++i) {
    int c = tid + i * 256;
    int row = c >> 3, pj = c & 7;
    uint4 v = *(const uint4*)(Ps + row * 64 + ((pj ^ (row & 7)) * 8));
    *(uint4*)(Ctx + ((size_t)(b * 2048 + qt * 128 + row)) * 1024 + h * 64 + pj * 8) = v;
  }
}

// ---------------- launch ----------------
extern "C" void kernel_launch(void* const* d_in, const int* in_sizes, int n_in,
                              void* d_out, int out_size, void* d_ws, size_t ws_size,
                              hipStream_t stream) {
  const float* query = (const float*)d_in[0];
  const float* key_  = (const float*)d_in[1];
  const float* value = (const float*)d_in[2];
  const float* Wq = (const float*)d_in[3];
  const float* bq = (const float*)d_in[4];
  const float* Wk = (const float*)d_in[5];
  const float* bk = (const float*)d_in[6];
  const float* Wv = (const float*)d_in[7];
  const float* bv = (const float*)d_in[8];
  const float* Wo = (const float*)d_in[9];
  const float* bo = (const float*)d_in[10];

  char* w = (char*)d_ws;
  unsigned short* Wb  = (unsigned short*)w; w += (size_t)4 * 1024 * 1024 * 2;  // Wq,Wk,Wv,Wo bf16
  unsigned short* Qp  = (unsigned short*)w; w += (size_t)8192 * 1024 * 2;      // [B,H,S,64]
  unsigned short* Kp  = (unsigned short*)w; w += (size_t)8192 * 1024 * 2;      // [B,H,S,64]
  unsigned short* VTp = (unsigned short*)w; w += (size_t)8192 * 1024 * 2;      // [B,H,64,S]
  unsigned short* Ctx = (unsigned short*)w; w += (size_t)8192 * 1024 * 2;      // [B,S,1024]

  // bf16 activations: query/key park in d_out (32 MB, dead until gemm_o);
  // value parks in the Ctx slot (dead once qkv_gemm completes, before attn writes Ctx).
  unsigned short* XqB = (unsigned short*)d_out;
  unsigned short* XkB = (unsigned short*)d_out + (size_t)8192 * 1024;
  unsigned short* XvB = Ctx;

  cvt_all<<<28672, 256, 0, stream>>>(Wq, Wk, Wv, Wo, query, key_, value,
                                     Wb, XqB, XkB, XvB);

  qkv_gemm<<<dim3(8, 64, 3), 256, 0, stream>>>(XqB, XkB, XvB, Wb,
                                               bq, bk, bv, Qp, Kp, VTp);

  attn_kernel<<<dim3(16, 16, 4), 256, 0, stream>>>(Qp, Kp, VTp, Ctx);

  gemm_o<<<dim3(8, 64), 256, 0, stream>>>(Ctx, Wb + (size_t)3 * 1048576, bo, (float*)d_out);
}

// Round 3
// 374.923 us; speedup vs baseline: 1.1072x; 1.0691x over previous
//
#include <hip/hip_runtime.h>
#include <stdint.h>

typedef __attribute__((ext_vector_type(8))) short short8;   // 8 x bf16 MFMA operand
typedef __attribute__((ext_vector_type(4))) float floatx4;  // MFMA accumulator

#define DEV __device__ __forceinline__

DEV unsigned short f2bf(float x) {  // fp32 -> bf16 RNE (epilogue-only)
  unsigned u = __float_as_uint(x);
  u += 0x7fffu + ((u >> 16) & 1u);
  return (unsigned short)(u >> 16);
}

// pack two fp32 -> two bf16 (round-half-up) in 3 VALU: 2 adds + v_perm
DEV unsigned pkbf(float hi, float lo) {
  return __builtin_amdgcn_perm(__float_as_uint(hi) + 0x8000u,
                               __float_as_uint(lo) + 0x8000u, 0x07060302u);
}

// single-instruction pack: dst = {lo16: bf16(a), hi16: bf16(b)} (RNE)
DEV unsigned cvtpk(float a, float b) {
  unsigned r;
  asm("v_cvt_pk_bf16_f32 %0, %1, %2" : "=v"(r) : "v"(a), "v"(b));
  return r;
}

DEV void load_lds16(const unsigned short* g, unsigned short* l) {
  __builtin_amdgcn_global_load_lds(
      (const __attribute__((address_space(1))) void*)g,
      (__attribute__((address_space(3))) void*)l, 16, 0, 0);
}

DEV void lds_fence() { asm volatile("" ::: "memory"); }  // wave-private LDS RAW/WAR ordering

// counted vmcnt + raw barrier (T4): never drain to 0 mid-loop
#define ASM_VMCNT(n) asm volatile("s_waitcnt vmcnt(" #n ")" ::: "memory")
DEV void sched_fence() { __builtin_amdgcn_sched_barrier(0); }

// ---------------- one-shot fp32 -> bf16 of all 7 tensors ----------------
__global__ void cvt_all(const float* __restrict__ Wq, const float* __restrict__ Wk,
                        const float* __restrict__ Wv, const float* __restrict__ Wo,
                        const float* __restrict__ Xq, const float* __restrict__ Xk,
                        const float* __restrict__ Xv,
                        unsigned short* __restrict__ Wb, unsigned short* __restrict__ XqB,
                        unsigned short* __restrict__ XkB, unsigned short* __restrict__ XvB) {
  int bid = blockIdx.x;
  const float* src;
  unsigned short* dst;
  int off;
  if (bid < 4096) {
    int sel = bid >> 10;
    src = sel == 0 ? Wq : sel == 1 ? Wk : sel == 2 ? Wv : Wo;
    dst = Wb + (size_t)sel * 1048576;
    off = bid & 1023;
  } else {
    bid -= 4096;
    int sel = bid >> 13;
    src = sel == 0 ? Xq : sel == 1 ? Xk : Xv;
    dst = sel == 0 ? XqB : sel == 1 ? XkB : XvB;
    off = bid & 8191;
  }
  int i = (off * 256 + threadIdx.x) * 4;
  float4 v = *(const float4*)(src + i);
  uint2 o;
  o.x = pkbf(v.y, v.x);
  o.y = pkbf(v.w, v.z);
  *(uint2*)(dst + i) = o;
}

// ---------------- fused QKV projection: depth-2 counted-vmcnt pipeline, grid (8,64,3) --------
// XCD swizzle: each XCD owns a contiguous 8-block s-span (2MB X + 2MB W = L2-resident).
#define SCQ (0.125f * 1.44269504089f)
__global__ __launch_bounds__(256, 3) void qkv_gemm(
    const unsigned short* __restrict__ XqB, const unsigned short* __restrict__ XkB,
    const unsigned short* __restrict__ XvB,
    const unsigned short* __restrict__ Wb,
    const float* __restrict__ bq, const float* __restrict__ bk, const float* __restrict__ bv,
    unsigned short* __restrict__ Qp, unsigned short* __restrict__ Kp,
    unsigned short* __restrict__ VTp) {
  __shared__ alignas(16) unsigned short Xs[3][128 * 32];
  __shared__ alignas(16) unsigned short Ws[3][128 * 32];
  const int z = blockIdx.z;
  const unsigned short* X = z == 0 ? XqB : z == 1 ? XkB : XvB;
  const unsigned short* W = Wb + (size_t)z * 1048576;
  const float* bias = z == 0 ? bq : z == 1 ? bk : bv;

  const int tid = threadIdx.x;
  const int lane = tid & 63, wave = tid >> 6;
  const int lcol = lane & 15, quad = lane >> 4;
  // XCD L2-locality remap (8 XCDs, linear id round-robins xcd = id&7):
  const int n2 = blockIdx.x + 8 * blockIdx.y;  // 0..511
  const int xcd = n2 & 7, ii = n2 >> 3;
  const int wo = (ii >> 3) * 128;              // d block 0..7
  const int xo = (xcd * 8 + (ii & 7)) * 128;   // s block: xcd owns s-span [xcd*8, xcd*8+8)
  const int wm = (wave & 1) * 64;
  const int wn = (wave >> 1) * 64;

  floatx4 acc[4][4];
  for (int mi = 0; mi < 4; ++mi)
    for (int ni = 0; ni < 4; ++ni)
      for (int r = 0; r < 4; ++r) acc[mi][ni][r] = 0.f;

  auto stage = [&](int kt, int buf) {  // 4 vmem ops / thread / tile
    const int k0 = kt * 32;
    int c = tid;
    load_lds16(W + (size_t)(wo + (c >> 2)) * 1024 + k0 + (c & 3) * 8, Ws[buf] + c * 8);
    load_lds16(X + (size_t)(xo + (c >> 2)) * 1024 + k0 + (c & 3) * 8, Xs[buf] + c * 8);
    c = tid + 256;
    load_lds16(W + (size_t)(wo + (c >> 2)) * 1024 + k0 + (c & 3) * 8, Ws[buf] + c * 8);
    load_lds16(X + (size_t)(xo + (c >> 2)) * 1024 + k0 + (c & 3) * 8, Xs[buf] + c * 8);
  };

  stage(0, 0);
  stage(1, 1);
  int cur = 0;
  for (int kt = 0; kt < 32; ++kt) {
    sched_fence();
    ASM_VMCNT(4);                    // tile kt landed; tile kt+1 still in flight
    __builtin_amdgcn_s_barrier();    // cross-wave visibility of tile kt
    sched_fence();
    int nb = cur + 2; if (nb >= 3) nb -= 3;
    stage((kt + 2) & 31, nb);        // wrap-issue keeps vmcnt count uniform at tail
    const unsigned short* Ab = (z < 2) ? Ws[cur] : Xs[cur];  // A rows (m)
    const unsigned short* Bb = (z < 2) ? Xs[cur] : Ws[cur];  // B rows (n)
    short8 af[4], bfr[4];
#pragma unroll
    for (int mi = 0; mi < 4; ++mi)
      af[mi] = *(const short8*)(Ab + (wm + mi * 16 + lcol) * 32 + quad * 8);
#pragma unroll
    for (int ni = 0; ni < 4; ++ni)
      bfr[ni] = *(const short8*)(Bb + (wn + ni * 16 + lcol) * 32 + quad * 8);
#pragma unroll
    for (int mi = 0; mi < 4; ++mi)
#pragma unroll
      for (int ni = 0; ni < 4; ++ni)
        acc[mi][ni] = __builtin_amdgcn_mfma_f32_16x16x32_bf16(af[mi], bfr[ni], acc[mi][ni], 0, 0, 0);
    cur = (cur == 2) ? 0 : cur + 1;
  }

  if (z < 2) {  // lane: d = base+quad*4+r (consecutive), s = ...+lcol -> packed uint2
    unsigned short* Out = z == 0 ? Qp : Kp;
    const float scl = z == 0 ? SCQ : 1.f;
#pragma unroll
    for (int mi = 0; mi < 4; ++mi) {
      int dbase = wo + wm + mi * 16 + quad * 4;
      float4 bv4 = *(const float4*)(bias + dbase);
      int h = dbase >> 6, dk = dbase & 63;
#pragma unroll
      for (int ni = 0; ni < 4; ++ni) {
        int sg = xo + wn + ni * 16 + lcol;  // = b*2048 + s
        int bb = sg >> 11, ss = sg & 2047;
        uint2 o;
        o.x = pkbf((acc[mi][ni][1] + bv4.y) * scl, (acc[mi][ni][0] + bv4.x) * scl);
        o.y = pkbf((acc[mi][ni][3] + bv4.w) * scl, (acc[mi][ni][2] + bv4.z) * scl);
        *(uint2*)(Out + ((size_t)(bb * 16 + h) * 2048 + ss) * 64 + dk) = o;
      }
    }
  } else {  // lane: s = base+quad*4+r (consecutive), d = ...+lcol -> packed uint2 into V^T
#pragma unroll
    for (int ni = 0; ni < 4; ++ni) {
      int dg = wo + wn + ni * 16 + lcol;
      float bvx = bias[dg];
      int h = dg >> 6, dk = dg & 63;
#pragma unroll
      for (int mi = 0; mi < 4; ++mi) {
        int sbase = xo + wm + mi * 16 + quad * 4;
        int bb = sbase >> 11, ss = sbase & 2047;
        uint2 o;
        o.x = pkbf(acc[mi][ni][1] + bvx, acc[mi][ni][0] + bvx);
        o.y = pkbf(acc[mi][ni][3] + bvx, acc[mi][ni][2] + bvx);
        *(uint2*)(VTp + ((size_t)(bb * 16 + h) * 64 + dk) * 2048 + ss) = o;
      }
    }
  }
}

// ---------------- final O-projection: fp32 out, depth-2 counted-vmcnt ----------------
__global__ __launch_bounds__(256, 3) void gemm_o(
    const unsigned short* __restrict__ A, const unsigned short* __restrict__ Bw,
    const float* __restrict__ bias, float* __restrict__ Out) {
  __shared__ alignas(16) unsigned short Cs[3][128 * 32];
  __shared__ alignas(16) unsigned short Wos[3][128 * 32];
  const int tid = threadIdx.x;
  const int lane = tid & 63, wave = tid >> 6;
  const int lcol = lane & 15, quad = lane >> 4;
  const int n2 = blockIdx.x + 8 * blockIdx.y;  // XCD L2-locality remap
  const int xcd = n2 & 7, ii = n2 >> 3;
  const int co = (ii >> 3) * 128;              // output-col block
  const int so = (xcd * 8 + (ii & 7)) * 128;   // s block
  const int wm = (wave & 1) * 64;
  const int wn = (wave >> 1) * 64;

  floatx4 acc[4][4];
  for (int mi = 0; mi < 4; ++mi)
    for (int ni = 0; ni < 4; ++ni)
      for (int r = 0; r < 4; ++r) acc[mi][ni][r] = 0.f;

  auto stage = [&](int kt, int buf) {
    const int k0 = kt * 32;
    int c = tid;
    load_lds16(Bw + (size_t)(co + (c >> 2)) * 1024 + k0 + (c & 3) * 8, Wos[buf] + c * 8);
    load_lds16(A  + (size_t)(so + (c >> 2)) * 1024 + k0 + (c & 3) * 8, Cs[buf] + c * 8);
    c = tid + 256;
    load_lds16(Bw + (size_t)(co + (c >> 2)) * 1024 + k0 + (c & 3) * 8, Wos[buf] + c * 8);
    load_lds16(A  + (size_t)(so + (c >> 2)) * 1024 + k0 + (c & 3) * 8, Cs[buf] + c * 8);
  };

  stage(0, 0);
  stage(1, 1);
  int cur = 0;
  for (int kt = 0; kt < 32; ++kt) {
    sched_fence();
    ASM_VMCNT(4);
    __builtin_amdgcn_s_barrier();
    sched_fence();
    int nb = cur + 2; if (nb >= 3) nb -= 3;
    stage((kt + 2) & 31, nb);
    short8 af[4], bfr[4];
#pragma unroll
    for (int mi = 0; mi < 4; ++mi)
      af[mi] = *(const short8*)(Wos[cur] + (wm + mi * 16 + lcol) * 32 + quad * 8);
#pragma unroll
    for (int ni = 0; ni < 4; ++ni)
      bfr[ni] = *(const short8*)(Cs[cur] + (wn + ni * 16 + lcol) * 32 + quad * 8);
#pragma unroll
    for (int mi = 0; mi < 4; ++mi)
#pragma unroll
      for (int ni = 0; ni < 4; ++ni)
        acc[mi][ni] = __builtin_amdgcn_mfma_f32_16x16x32_bf16(af[mi], bfr[ni], acc[mi][ni], 0, 0, 0);
    cur = (cur == 2) ? 0 : cur + 1;
  }
#pragma unroll
  for (int mi = 0; mi < 4; ++mi) {
    int cb = co + wm + mi * 16 + quad * 4;  // 4 consecutive output cols
    float4 bv4 = *(const float4*)(bias + cb);
#pragma unroll
    for (int ni = 0; ni < 4; ++ni) {
      int sg = so + wn + ni * 16 + lcol;
      float4 o;
      o.x = acc[mi][ni][0] + bv4.x;
      o.y = acc[mi][ni][1] + bv4.y;
      o.z = acc[mi][ni][2] + bv4.z;
      o.w = acc[mi][ni][3] + bv4.w;
      *(float4*)(Out + (size_t)sg * 1024 + cb) = o;
    }
  }
}

// ---------------- flash attention: one block = (b, h, 128 q rows) ----------------
// Round-3: VALU diet. L accumulated via ones-column MFMA (rescales with O for free,
// lands in C-row layout -> no epilogue shfl). P-pack via v_cvt_pk_bf16_f32 (1 op / 2 vals).
// max3 trees; defer-max decided on lane-local max (shfl-reduce only on non-skip iters).
// XCD swizzle: each XCD owns 8 (b,h) pairs (4MB KV = L2-resident across its 16 qt-blocks).
__global__ __launch_bounds__(256, 4) void attn_kernel(
    const unsigned short* __restrict__ Qp, const unsigned short* __restrict__ Kp,
    const unsigned short* __restrict__ VTp, unsigned short* __restrict__ Ctx) {
  __shared__ alignas(16) unsigned short Ks[2][64 * 64];  // K tiles, dbuf (16KB)
  __shared__ alignas(16) unsigned short Vt[64 * 64];     // V^T tile (8KB)
  __shared__ alignas(16) unsigned short Ps[128 * 64];    // Q stage -> P -> O stage (16KB)

  const int tid = threadIdx.x;
  const int lane = tid & 63, wave = tid >> 6;
  const int lcol = lane & 15, quad = lane >> 4;
  const int wq = wave * 32;
  // XCD L2-locality remap: n = qt + 16*hb; xcd owns hb-span of 8 (4MB K+V)
  const int n = blockIdx.x + 16 * (blockIdx.y + 16 * blockIdx.z);
  const int xcd = n & 7, ii = n >> 3;
  const int hb = xcd * 8 + (ii & 7);  // = b*16 + h
  const int qt = ii >> 3;
  const size_t bh = (size_t)hb * 2048 * 64;
  const int b = hb >> 4;
  const unsigned short* Qb = Qp + bh + (size_t)qt * 128 * 64;
  const unsigned short* Kb = Kp + bh;
  const unsigned short* VTb = VTp + bh;

  // prologue: Q tile into Ps (swizzled) + K tile 0 into Ks[0]
#pragma unroll
  for (int i = 0; i < 4; ++i) {
    int p = tid + i * 256;
    int row = p >> 3, pj = p & 7;
    load_lds16(Qb + row * 64 + ((pj ^ (row & 7)) * 8), Ps + p * 8);
  }
#pragma unroll
  for (int i = 0; i < 2; ++i) {
    int p = tid + i * 256;
    int kr = p >> 3, kj = p & 7;
    load_lds16(Kb + kr * 64 + ((kj ^ (kr & 7)) * 8), Ks[0] + p * 8);
  }
  __syncthreads();  // Q + K0 resident

  short8 qf[2][2];
#pragma unroll
  for (int ni = 0; ni < 2; ++ni)
#pragma unroll
    for (int ks = 0; ks < 2; ++ks) {
      int row = wq + ni * 16 + lcol;
      qf[ni][ks] = *(const short8*)(Ps + row * 64 + (((ks * 4 + quad) ^ (row & 7)) * 8));
    }

  // bf16 1.0 splat: B-operand for the L (row-sum) MFMA
  short8 ones;
#pragma unroll
  for (int j = 0; j < 8; ++j) ones[j] = (short)0x3f80;

  float M[2] = {-1e30f, -1e30f};
  floatx4 Oacc[2][4];
  floatx4 OaccL[2];  // L in C-row layout: OaccL[mi][r] = sum_k P[q=wq+mi*16+quad*4+r][k]
  for (int mi = 0; mi < 2; ++mi) {
    for (int nd = 0; nd < 4; ++nd)
      for (int r = 0; r < 4; ++r) Oacc[mi][nd][r] = 0.f;
    for (int r = 0; r < 4; ++r) OaccL[mi][r] = 0.f;
  }

  for (int jt = 0; jt < 32; ++jt) {
    const int cur = jt & 1;
    // issue V(jt) first (2 ops), then K(jt+1) (2 ops) -> vmcnt(2) waits exactly V
#pragma unroll
    for (int i = 0; i < 2; ++i) {
      int p = tid + i * 256;
      int vr = p >> 3, vj = p & 7;
      load_lds16(VTb + (size_t)vr * 2048 + jt * 64 + ((vj ^ (vr & 7)) * 8), Vt + p * 8);
    }
    const int jn = (jt + 1) & 31;  // wrap-issue at tail keeps vmcnt count uniform
#pragma unroll
    for (int i = 0; i < 2; ++i) {
      int p = tid + i * 256;
      int kr = p >> 3, kj = p & 7;
      load_lds16(Kb + (size_t)jn * 4096 + kr * 64 + ((kj ^ (kr & 7)) * 8), Ks[cur ^ 1] + p * 8);
    }

    // S^T = K @ Q^T  (Q pre-scaled: sacc already in base-2 logit units)
    const unsigned short* Kc = Ks[cur];
    floatx4 sacc[4][2];
    for (int mi = 0; mi < 4; ++mi)
      for (int ni = 0; ni < 2; ++ni)
        for (int r = 0; r < 4; ++r) sacc[mi][ni][r] = 0.f;
#pragma unroll
    for (int mi = 0; mi < 4; ++mi) {
      int row = mi * 16 + lcol;
      int sw = (row & 7);
      short8 kf0 = *(const short8*)(Kc + row * 64 + ((quad ^ sw) * 8));
      short8 kf1 = *(const short8*)(Kc + row * 64 + (((4 + quad) ^ sw) * 8));
#pragma unroll
      for (int ni = 0; ni < 2; ++ni) {
        sacc[mi][ni] = __builtin_amdgcn_mfma_f32_16x16x32_bf16(kf0, qf[ni][0], sacc[mi][ni], 0, 0, 0);
        sacc[mi][ni] = __builtin_amdgcn_mfma_f32_16x16x32_bf16(kf1, qf[ni][1], sacc[mi][ni], 0, 0, 0);
      }
    }

    // ---- lane-local max via max3 trees ----
    float lmax[2];
#pragma unroll
    for (int ni = 0; ni < 2; ++ni) {
      float a0 = fmaxf(fmaxf(sacc[0][ni][0], sacc[0][ni][1]), sacc[0][ni][2]);
      float a1 = fmaxf(fmaxf(sacc[0][ni][3], sacc[1][ni][0]), sacc[1][ni][1]);
      float a2 = fmaxf(fmaxf(sacc[1][ni][2], sacc[1][ni][3]), sacc[2][ni][0]);
      float a3 = fmaxf(fmaxf(sacc[2][ni][1], sacc[2][ni][2]), sacc[2][ni][3]);
      float a4 = fmaxf(fmaxf(sacc[3][ni][0], sacc[3][ni][1]), sacc[3][ni][2]);
      float b0 = fmaxf(fmaxf(a0, a1), a2);
      float b1 = fmaxf(fmaxf(a3, a4), sacc[3][ni][3]);
      lmax[ni] = fmaxf(b0, b1);
    }
    // defer-max: skip the reduce+rescale when no lane's local max exceeds M+8
    const int skip = __all((lmax[0] <= M[0] + 8.f) & (lmax[1] <= M[1] + 8.f));
    if (!skip) {
      float alpha[2];
#pragma unroll
      for (int ni = 0; ni < 2; ++ni) {
        float m = lmax[ni];
        m = fmaxf(m, __shfl_xor(m, 16));
        m = fmaxf(m, __shfl_xor(m, 32));
        float mnew = fmaxf(M[ni], m);
        alpha[ni] = exp2f(M[ni] - mnew);
        M[ni] = mnew;
      }
#pragma unroll
      for (int mi = 0; mi < 2; ++mi)
#pragma unroll
        for (int r = 0; r < 4; ++r) {
          float a = __shfl(alpha[mi], quad * 4 + r);
          floatx4 av = {a, a, a, a};
#pragma unroll
          for (int nd = 0; nd < 4; ++nd) Oacc[mi][nd] *= av;
          OaccL[mi][r] *= a;
        }
    }
    // exp (no sum -- L comes from the ones-column MFMA)
#pragma unroll
    for (int ni = 0; ni < 2; ++ni) {
      floatx4 mv = {M[ni], M[ni], M[ni], M[ni]};
#pragma unroll
      for (int mi = 0; mi < 4; ++mi) {
        floatx4 t = sacc[mi][ni] - mv;
        sacc[mi][ni][0] = exp2f(t[0]);
        sacc[mi][ni][1] = exp2f(t[1]);
        sacc[mi][ni][2] = exp2f(t[2]);
        sacc[mi][ni][3] = exp2f(t[3]);
      }
    }

    // P -> Ps (wave-private rows); cvt_pk packed writes; fence-ordered
#pragma unroll
    for (int ni = 0; ni < 2; ++ni) {
      int q = wq + ni * 16 + lcol;
      int sw = q & 7;
#pragma unroll
      for (int mi = 0; mi < 4; ++mi) {
        uint2 pw;
        pw.x = cvtpk(sacc[mi][ni][0], sacc[mi][ni][1]);
        pw.y = cvtpk(sacc[mi][ni][2], sacc[mi][ni][3]);
        int j = 2 * mi + (quad >> 1);
        *(uint2*)(Ps + q * 64 + ((j ^ sw) * 8) + (quad & 1) * 4) = pw;
      }
    }
    lds_fence();

    sched_fence();
    ASM_VMCNT(2);                  // V(jt) landed; K(jt+1) still in flight (T4)
    __builtin_amdgcn_s_barrier();  // B1: all waves' V-loads visible
    sched_fence();

    // PV from Vt & Ps (+ ones-column row-sum into OaccL)
#pragma unroll
    for (int kk = 0; kk < 2; ++kk) {
      short8 pf[2];
#pragma unroll
      for (int mi = 0; mi < 2; ++mi) {
        int q = wq + mi * 16 + lcol;
        pf[mi] = *(const short8*)(Ps + q * 64 + (((kk * 4 + quad) ^ (q & 7)) * 8));
      }
#pragma unroll
      for (int nd = 0; nd < 4; ++nd) {
        int d = nd * 16 + lcol;
        short8 vf = *(const short8*)(Vt + d * 64 + (((kk * 4 + quad) ^ (d & 7)) * 8));
#pragma unroll
        for (int mi = 0; mi < 2; ++mi)
          Oacc[mi][nd] = __builtin_amdgcn_mfma_f32_16x16x32_bf16(pf[mi], vf, Oacc[mi][nd], 0, 0, 0);
      }
#pragma unroll
      for (int mi = 0; mi < 2; ++mi)
        OaccL[mi] = __builtin_amdgcn_mfma_f32_16x16x32_bf16(pf[mi], ones, OaccL[mi], 0, 0, 0);
    }
    lds_fence();
    __syncthreads();  // B2: K(jt+1) landed + all waves done with Vt/Ks[cur]
  }

  // epilogue: O/L -> bf16 into Ps (swizzled, wave-private rows), then coalesced store.
  // OaccL is already in C-row layout -> no shfl needed.
#pragma unroll
  for (int mi = 0; mi < 2; ++mi)
#pragma unroll
    for (int r = 0; r < 4; ++r) {
      float li = 1.f / OaccL[mi][r];
      int q = wq + mi * 16 + quad * 4 + r;
      int sw = q & 7;
#pragma unroll
      for (int nd = 0; nd < 4; ++nd) {
        int j = 2 * nd + (lcol >> 3);
        Ps[q * 64 + ((j ^ sw) * 8) + (lcol & 7)] = f2bf(Oacc[mi][nd][r] * li);
      }
    }
  __syncthreads();
#pragma unroll
  for (int i = 0; i < 4; ++i) {
    int c = tid + i * 256;
    int row = c >> 3, pj = c & 7;
    uint4 v = *(const uint4*)(Ps + row * 64 + ((pj ^ (row & 7)) * 8));
    *(uint4*)(Ctx + ((size_t)(b * 2048 + qt * 128 + row)) * 1024 + (hb & 15) * 64 + pj * 8) = v;
  }
}

// ---------------- launch ----------------
extern "C" void kernel_launch(void* const* d_in, const int* in_sizes, int n_in,
                              void* d_out, int out_size, void* d_ws, size_t ws_size,
                              hipStream_t stream) {
  const float* query = (const float*)d_in[0];
  const float* key_  = (const float*)d_in[1];
  const float* value = (const float*)d_in[2];
  const float* Wq = (const float*)d_in[3];
  const float* bq = (const float*)d_in[4];
  const float* Wk = (const float*)d_in[5];
  const float* bk = (const float*)d_in[6];
  const float* Wv = (const float*)d_in[7];
  const float* bv = (const float*)d_in[8];
  const float* Wo = (const float*)d_in[9];
  const float* bo = (const float*)d_in[10];

  char* w = (char*)d_ws;
  unsigned short* Wb  = (unsigned short*)w; w += (size_t)4 * 1024 * 1024 * 2;  // Wq,Wk,Wv,Wo bf16
  unsigned short* Qp  = (unsigned short*)w; w += (size_t)8192 * 1024 * 2;      // [B,H,S,64]
  unsigned short* Kp  = (unsigned short*)w; w += (size_t)8192 * 1024 * 2;      // [B,H,S,64]
  unsigned short* VTp = (unsigned short*)w; w += (size_t)8192 * 1024 * 2;      // [B,H,64,S]
  unsigned short* Ctx = (unsigned short*)w; w += (size_t)8192 * 1024 * 2;      // [B,S,1024]

  // bf16 activations: query/key park in d_out (32 MB, dead until gemm_o);
  // value parks in the Ctx slot (dead once qkv_gemm completes, before attn writes Ctx).
  unsigned short* XqB = (unsigned short*)d_out;
  unsigned short* XkB = (unsigned short*)d_out + (size_t)8192 * 1024;
  unsigned short* XvB = Ctx;

  cvt_all<<<28672, 256, 0, stream>>>(Wq, Wk, Wv, Wo, query, key_, value,
                                     Wb, XqB, XkB, XvB);

  qkv_gemm<<<dim3(8, 64, 3), 256, 0, stream>>>(XqB, XkB, XvB, Wb,
                                               bq, bk, bv, Qp, Kp, VTp);

  attn_kernel<<<dim3(16, 16, 4), 256, 0, stream>>>(Qp, Kp, VTp, Ctx);

  gemm_o<<<dim3(8, 64), 256, 0, stream>>>(Ctx, Wb + (size_t)3 * 1048576, bo, (float*)d_out);
}